// Round 3
// baseline (29059.045 us; speedup 1.0000x reference)
//
#include <hip/hip_runtime.h>
#include <math.h>

// ESN recurrence: h_k = 0.99*h_{k-1} + 0.01*tanh(Win x_{k-1} + Wh h_{k-1}), k=1..8192
// out[k-101][0:2048] = h_k (k>=101), out[.][2048:2112] = x_{k-1}
//
// R3: 64 WGs x 32 rows (was 128 x 16). Two rows per thread share the same LDS
// h reads (FMAs double, LDS traffic unchanged). Halves the sync population:
// device poll traffic 2MB -> 1MB per round, publishers 128 -> 64 (less skew).
// Fused data+tag 8B words, double-buffered; race-free by the dissemination
// argument (a WG overwrites tag k with k+2 only after observing all k+1 tags,
// each of which was stored after that WG finished reading the k words).

#define NWG        64
#define ROWS_PER_WG 32
#define T_STEPS    8192
#define WARMUP     100
#define RSIZE      2048
#define ISIZE      64
#define OUTCOLS    2112

__global__ __launch_bounds__(256) void init_ws_kernel(unsigned long long* buf0,
                                                      unsigned long long* buf1) {
    int t = blockIdx.x * blockDim.x + threadIdx.x;
    if (t < RSIZE) {
        buf0[t] = 0ull;                      // (tag=0, h_0=0.0f)
        buf1[t] = 0xFFFFFFFF00000000ull;     // invalid tag — first valid write is tag 1
    }
}

__global__ __launch_bounds__(256) void xcopy_kernel(const float* __restrict__ x,
                                                    float* __restrict__ out) {
    int t = blockIdx.x * blockDim.x + threadIdx.x;
    if (t >= (T_STEPS - WARMUP) * ISIZE) return;
    int rowo = t >> 6;          // output row 0..8091
    int j    = t & 63;
    out[(size_t)rowo * OUTCOLS + RSIZE + j] = x[(size_t)(rowo + WARMUP) * ISIZE + j];
}

__global__ __launch_bounds__(256, 1) void esn_scan_kernel(
    const float* __restrict__ x,    // [8192][64]
    const float* __restrict__ Win,  // [2048][64]
    const float* __restrict__ Wh,   // [2048][2048]
    float* __restrict__ out,        // [8092][2112]
    unsigned long long* buf0,       // [2048] tagged h slots, even steps (incl. h_0)
    unsigned long long* buf1)       // [2048] tagged h slots, odd steps
{
    __shared__ float hs[RSIZE];     // staged h_{k-1}, bank-swizzled

    const int tid = threadIdx.x;    // 0..255
    const int wg  = blockIdx.x;     // 0..63
    const int r   = tid >> 4;       // 0..15
    const int c   = tid & 15;       // 128-col chunk index, 0..15
    const int rowA = wg * ROWS_PER_WG + r;        // first owned row
    const int rowB = rowA + 16;                   // second owned row

    // One-time register-resident weights (2 rows/thread, 64 float4 = 256 VGPRs).
    const float4 winA = *(const float4*)(Win + (size_t)rowA * ISIZE + c * 4);
    const float4 winB = *(const float4*)(Win + (size_t)rowB * ISIZE + c * 4);
    float4 whA[32], whB[32];
    const float4* whpA = (const float4*)(Wh + (size_t)rowA * RSIZE + c * 128);
    const float4* whpB = (const float4*)(Wh + (size_t)rowB * RSIZE + c * 128);
#pragma unroll
    for (int j = 0; j < 32; ++j) whA[j] = whpA[j];
#pragma unroll
    for (int j = 0; j < 32; ++j) whB[j] = whpB[j];

    float hA = 0.0f, hB = 0.0f;     // owned rows' h (replicated over the 16 c-lanes)

    for (int k = 1; k <= T_STEPS; ++k) {
        // x load issued before the poll so it's in flight during the spin
        const float4 xv = *(const float4*)(x + (size_t)(k - 1) * ISIZE + c * 4);

        // ---- poll the tagged h_{k-1} words directly ----
        const unsigned long long* bp = ((k - 1) & 1) ? buf1 : buf0;
        const unsigned expect = (unsigned)(k - 1);
        unsigned long long w[8];
        unsigned mask = 0xFFu;
        while (mask) {
#pragma unroll
            for (int s = 0; s < 8; ++s) {
                if (mask & (1u << s)) {
                    w[s] = __hip_atomic_load(bp + s * 256 + tid, __ATOMIC_RELAXED,
                                             __HIP_MEMORY_SCOPE_AGENT);
                }
            }
#pragma unroll
            for (int s = 0; s < 8; ++s) {
                if ((mask & (1u << s)) && (unsigned)(w[s] >> 32) == expect) {
                    mask &= ~(1u << s);
                }
            }
        }

        __syncthreads();  // previous step's LDS reads finished before overwrite

        // ---- stage h_{k-1} -> LDS (swizzle: chunk (cc,jj) at rot (jj+cc)&31) ----
#pragma unroll
        for (int s = 0; s < 8; ++s) {
            int idx = s * 256 + tid;                    // 0..2047
            int cc = idx >> 7;
            int jj = (idx >> 2) & 31;
            int e  = idx & 3;
            hs[cc * 128 + (((jj + cc) & 31) << 2) + e] = __uint_as_float((unsigned)w[s]);
        }
        __syncthreads();

        // ---- y[row] = Win[row]·x_{k-1} + Wh[row]·h_{k-1}, two rows sharing hv ----
        float pA = winA.x * xv.x + winA.y * xv.y + winA.z * xv.z + winA.w * xv.w;
        float pB = winB.x * xv.x + winB.y * xv.y + winB.z * xv.z + winB.w * xv.w;
        const float* hrow = hs + c * 128;
#pragma unroll
        for (int j = 0; j < 32; ++j) {
            const float4 hv = *(const float4*)(hrow + (((j + c) & 31) << 2));
            pA += whA[j].x * hv.x + whA[j].y * hv.y + whA[j].z * hv.z + whA[j].w * hv.w;
            pB += whB[j].x * hv.x + whB[j].y * hv.y + whB[j].z * hv.z + whB[j].w * hv.w;
        }
        // butterfly over the 16 c-lanes (c = low 4 lane bits)
        pA += __shfl_xor(pA, 1);  pB += __shfl_xor(pB, 1);
        pA += __shfl_xor(pA, 2);  pB += __shfl_xor(pB, 2);
        pA += __shfl_xor(pA, 4);  pB += __shfl_xor(pB, 4);
        pA += __shfl_xor(pA, 8);  pB += __shfl_xor(pB, 8);

        hA = 0.99f * hA + 0.01f * tanhf(pA);
        hB = 0.99f * hB + 0.01f * tanhf(pB);

        // ---- publish (tag=k, h_k); write output rows ----
        if (c == 0) {
            unsigned long long* bc = (k & 1) ? buf1 : buf0;
            unsigned long long tagk = (unsigned long long)(unsigned)k << 32;
            __hip_atomic_store(bc + rowA, tagk | __float_as_uint(hA),
                               __ATOMIC_RELAXED, __HIP_MEMORY_SCOPE_AGENT);
            __hip_atomic_store(bc + rowB, tagk | __float_as_uint(hB),
                               __ATOMIC_RELAXED, __HIP_MEMORY_SCOPE_AGENT);
            if (k >= WARMUP + 1) {
                float* orow = out + (size_t)(k - (WARMUP + 1)) * OUTCOLS;
                orow[rowA] = hA;
                orow[rowB] = hB;
            }
        }
        // no barrier here: next iteration's poll tolerates in-flight stores
    }
}

extern "C" void kernel_launch(void* const* d_in, const int* in_sizes, int n_in,
                              void* d_out, int out_size, void* d_ws, size_t ws_size,
                              hipStream_t stream) {
    const float* x   = (const float*)d_in[0];  // [8192*64]
    const float* Win = (const float*)d_in[1];  // [2048*64]
    const float* Wh  = (const float*)d_in[2];  // [2048*2048]
    float* out = (float*)d_out;                // [8092*2112]

    char* ws = (char*)d_ws;
    unsigned long long* buf0 = (unsigned long long*)ws;            // 16 KB
    unsigned long long* buf1 = (unsigned long long*)(ws + RSIZE * 8);

    // init tagged buffers (ws is poisoned 0xAA before every timed launch)
    init_ws_kernel<<<8, 256, 0, stream>>>(buf0, buf1);

    // x-part of the output, independent of the recurrence
    {
        int n = (T_STEPS - WARMUP) * ISIZE;
        xcopy_kernel<<<(n + 255) / 256, 256, 0, stream>>>(x, out);
    }

    // the sequential scan: 64 persistent workgroups
    esn_scan_kernel<<<NWG, 256, 0, stream>>>(x, Win, Wh, out, buf0, buf1);
}

// Round 4
// 23443.776 us; speedup vs baseline: 1.2395x; 1.2395x over previous
//
#include <hip/hip_runtime.h>
#include <math.h>

// ESN recurrence: h_k = 0.99*h_{k-1} + 0.01*tanh(Win x_{k-1} + Wh h_{k-1}), k=1..8192
// out[k-101][0:2048] = h_k (k>=101), out[.][2048:2112] = x_{k-1}
//
// R4: back to 128 WGs x 16 rows (R2 sync shape), but with the compute section
// fixed: 32 individually-NAMED float4 weight registers (R2/R3's float4 wh[32]
// array was never SROA'd -> scratch reloads every step; VGPR_Count 108 proved
// it). Strided chunk->column mapping removes the LDS swizzle (stage writes are
// stride-1; reads are 64-consecutive-float = 2-way bank aliasing = free).
// Overflow-safe exp2-based tanh replaces libm tanhf.

#define NWG        128
#define ROWS_PER_WG 16
#define T_STEPS    8192
#define WARMUP     100
#define RSIZE      2048
#define ISIZE      64
#define OUTCOLS    2112

__global__ __launch_bounds__(256) void init_ws_kernel(unsigned long long* buf0,
                                                      unsigned long long* buf1) {
    int t = blockIdx.x * blockDim.x + threadIdx.x;
    if (t < RSIZE) {
        buf0[t] = 0ull;                      // (tag=0, h_0=0.0f)
        buf1[t] = 0xFFFFFFFF00000000ull;     // invalid tag — first valid write is tag 1
    }
}

__global__ __launch_bounds__(256) void xcopy_kernel(const float* __restrict__ x,
                                                    float* __restrict__ out) {
    int t = blockIdx.x * blockDim.x + threadIdx.x;
    if (t >= (T_STEPS - WARMUP) * ISIZE) return;
    int rowo = t >> 6;          // output row 0..8091
    int j    = t & 63;
    out[(size_t)rowo * OUTCOLS + RSIZE + j] = x[(size_t)(rowo + WARMUP) * ISIZE + j];
}

// thread c (0..15) owns float4 chunks {16*j + c : j=0..31} of its row:
// columns [64*j + 4*c, 64*j + 4*c + 4). Covers all 2048 columns across c.
#define W_FOREACH(F) \
    F(0)  F(1)  F(2)  F(3)  F(4)  F(5)  F(6)  F(7)  \
    F(8)  F(9)  F(10) F(11) F(12) F(13) F(14) F(15) \
    F(16) F(17) F(18) F(19) F(20) F(21) F(22) F(23) \
    F(24) F(25) F(26) F(27) F(28) F(29) F(30) F(31)

__global__ __launch_bounds__(256, 1) void esn_scan_kernel(
    const float* __restrict__ x,    // [8192][64]
    const float* __restrict__ Win,  // [2048][64]
    const float* __restrict__ Wh,   // [2048][2048]
    float* __restrict__ out,        // [8092][2112]
    unsigned long long* buf0,       // [2048] tagged h slots, even steps (incl. h_0)
    unsigned long long* buf1)       // [2048] tagged h slots, odd steps
{
    __shared__ float hs[RSIZE];     // staged h_{k-1}, plain layout hs[col]

    const int tid = threadIdx.x;    // 0..255
    const int wg  = blockIdx.x;     // 0..127
    const int r   = tid >> 4;       // row within WG, 0..15
    const int c   = tid & 15;       // chunk lane, 0..15
    const int row = wg * ROWS_PER_WG + r;

    // One-time register-resident weights: 32 NAMED float4 scalars (128 VGPRs).
    const float4* whp4 = (const float4*)(Wh + (size_t)row * RSIZE);
#define DECL_W(J) const float4 w##J = whp4[16 * J + c];
    W_FOREACH(DECL_W)
#undef DECL_W
    const float4 winf = *(const float4*)(Win + (size_t)row * ISIZE + c * 4);

    float hcur = 0.0f;              // this row's h (replicated over the 16 c-lanes)

    for (int k = 1; k <= T_STEPS; ++k) {
        // x load issued before the poll so it's in flight during the spin
        const float4 xv = *(const float4*)(x + (size_t)(k - 1) * ISIZE + c * 4);

        // ---- poll the tagged h_{k-1} words directly (data+tag fused) ----
        const unsigned long long* bp = ((k - 1) & 1) ? buf1 : buf0;
        const unsigned expect = (unsigned)(k - 1);
        unsigned long long w[8];
        unsigned mask = 0xFFu;
        while (mask) {
#pragma unroll
            for (int s = 0; s < 8; ++s) {
                if (mask & (1u << s)) {
                    w[s] = __hip_atomic_load(bp + s * 256 + tid, __ATOMIC_RELAXED,
                                             __HIP_MEMORY_SCOPE_AGENT);
                }
            }
#pragma unroll
            for (int s = 0; s < 8; ++s) {
                if ((mask & (1u << s)) && (unsigned)(w[s] >> 32) == expect) {
                    mask &= ~(1u << s);
                }
            }
        }

        __syncthreads();  // previous step's LDS reads finished before overwrite

        // ---- stage h_{k-1} -> LDS, plain layout (stride-1 writes) ----
#pragma unroll
        for (int s = 0; s < 8; ++s) {
            hs[s * 256 + tid] = __uint_as_float((unsigned)w[s]);
        }
        __syncthreads();

        // ---- y[row] = Win[row]·x_{k-1} + Wh[row]·h_{k-1} ----
        float p = winf.x * xv.x + winf.y * xv.y + winf.z * xv.z + winf.w * xv.w;
        const float* hb = hs + 4 * c;
#define FMA_W(J) { const float4 hv = *(const float4*)(hb + 64 * J); \
                   p += w##J.x * hv.x + w##J.y * hv.y + w##J.z * hv.z + w##J.w * hv.w; }
        W_FOREACH(FMA_W)
#undef FMA_W

        // butterfly over the 16 c-lanes (c = low 4 lane bits)
        p += __shfl_xor(p, 1);
        p += __shfl_xor(p, 2);
        p += __shfl_xor(p, 4);
        p += __shfl_xor(p, 8);

        // overflow-safe fast tanh: tanh(p) = sign(p) * (1 - 2/(e^{2|p|}+1))
        {
            float ax = fabsf(p);
            float e  = __expf(2.0f * ax);        // v_exp_f32; inf-safe
            float t  = 1.0f - 2.0f / (e + 1.0f);
            t = copysignf(t, p);
            hcur = 0.99f * hcur + 0.01f * t;
        }

        // ---- publish (tag=k, h_k) first, then the output row ----
        if (c == 0) {
            unsigned long long* bc = (k & 1) ? buf1 : buf0;
            unsigned long long wv = ((unsigned long long)(unsigned)k << 32)
                                  | (unsigned long long)__float_as_uint(hcur);
            __hip_atomic_store(bc + row, wv, __ATOMIC_RELAXED,
                               __HIP_MEMORY_SCOPE_AGENT);
            if (k >= WARMUP + 1) {
                out[(size_t)(k - (WARMUP + 1)) * OUTCOLS + row] = hcur;
            }
        }
        // no barrier here: next iteration's poll tolerates in-flight stores
    }
}

extern "C" void kernel_launch(void* const* d_in, const int* in_sizes, int n_in,
                              void* d_out, int out_size, void* d_ws, size_t ws_size,
                              hipStream_t stream) {
    const float* x   = (const float*)d_in[0];  // [8192*64]
    const float* Win = (const float*)d_in[1];  // [2048*64]
    const float* Wh  = (const float*)d_in[2];  // [2048*2048]
    float* out = (float*)d_out;                // [8092*2112]

    char* ws = (char*)d_ws;
    unsigned long long* buf0 = (unsigned long long*)ws;            // 16 KB
    unsigned long long* buf1 = (unsigned long long*)(ws + RSIZE * 8);

    // init tagged buffers (ws is poisoned 0xAA before every timed launch)
    init_ws_kernel<<<8, 256, 0, stream>>>(buf0, buf1);

    // x-part of the output, independent of the recurrence
    {
        int n = (T_STEPS - WARMUP) * ISIZE;
        xcopy_kernel<<<(n + 255) / 256, 256, 0, stream>>>(x, out);
    }

    // the sequential scan: 128 persistent workgroups (1 per CU)
    esn_scan_kernel<<<NWG, 256, 0, stream>>>(x, Win, Wh, out, buf0, buf1);
}

// Round 5
// 21983.110 us; speedup vs baseline: 1.3219x; 1.0664x over previous
//
#include <hip/hip_runtime.h>
#include <math.h>

// ESN recurrence: h_k = 0.99*h_{k-1} + 0.01*tanh(Win x_{k-1} + Wh h_{k-1}), k=1..8192
// out[k-101][0:2048] = h_k (k>=101), out[.][2048:2112] = x_{k-1}
//
// R5: R4 + REAL register residency for the 128 weight floats per thread.
// R4's named float4s were sunk back into the loop by the compiler
// (VGPR_Count=96 proved it) -> ~128KB/CU/step weight re-fetch from L2.
// Fix: load into scalar locals and pin each through asm volatile("" : "+v")
// OUTSIDE the loop — volatile asm can't be sunk/rematerialized, so the values
// must stay live across the whole scan (512-VGPR budget at launch_bounds(256,1)).
// Also: double-buffered LDS h stage -> one __syncthreads per step instead of two
// (safe: a write to hs[par] at step k is ordered after all reads of hs[par] at
// step k-2 via the step k-1 barrier).

#define NWG        128
#define ROWS_PER_WG 16
#define T_STEPS    8192
#define WARMUP     100
#define RSIZE      2048
#define ISIZE      64
#define OUTCOLS    2112

__global__ __launch_bounds__(256) void init_ws_kernel(unsigned long long* buf0,
                                                      unsigned long long* buf1) {
    int t = blockIdx.x * blockDim.x + threadIdx.x;
    if (t < RSIZE) {
        buf0[t] = 0ull;                      // (tag=0, h_0=0.0f)
        buf1[t] = 0xFFFFFFFF00000000ull;     // invalid tag — first valid write is tag 1
    }
}

__global__ __launch_bounds__(256) void xcopy_kernel(const float* __restrict__ x,
                                                    float* __restrict__ out) {
    int t = blockIdx.x * blockDim.x + threadIdx.x;
    if (t >= (T_STEPS - WARMUP) * ISIZE) return;
    int rowo = t >> 6;          // output row 0..8091
    int j    = t & 63;
    out[(size_t)rowo * OUTCOLS + RSIZE + j] = x[(size_t)(rowo + WARMUP) * ISIZE + j];
}

// thread c (0..15) owns float4 chunks {16*j + c : j=0..31} of its row:
// columns [64*j + 4*c, 64*j + 4*c + 4). Covers all 2048 columns across c.
#define W_FOREACH(F) \
    F(0)  F(1)  F(2)  F(3)  F(4)  F(5)  F(6)  F(7)  \
    F(8)  F(9)  F(10) F(11) F(12) F(13) F(14) F(15) \
    F(16) F(17) F(18) F(19) F(20) F(21) F(22) F(23) \
    F(24) F(25) F(26) F(27) F(28) F(29) F(30) F(31)

__global__ __launch_bounds__(256, 1) void esn_scan_kernel(
    const float* __restrict__ x,    // [8192][64]
    const float* __restrict__ Win,  // [2048][64]
    const float* __restrict__ Wh,   // [2048][2048]
    float* __restrict__ out,        // [8092][2112]
    unsigned long long* buf0,       // [2048] tagged h slots, even steps (incl. h_0)
    unsigned long long* buf1)       // [2048] tagged h slots, odd steps
{
    __shared__ float hs[2][RSIZE];  // double-buffered staged h_{k-1}

    const int tid = threadIdx.x;    // 0..255
    const int wg  = blockIdx.x;     // 0..127
    const int r   = tid >> 4;       // row within WG, 0..15
    const int c   = tid & 15;       // chunk lane, 0..15
    const int row = wg * ROWS_PER_WG + r;

    // One-time weights: 128 scalar floats, pinned into VGPRs by volatile asm
    // (cannot be sunk into the loop or rematerialized).
    const float4* whp4 = (const float4*)(Wh + (size_t)row * RSIZE);
#define DECL_W(J) \
    float w##J##x, w##J##y, w##J##z, w##J##w; \
    { float4 t = whp4[16 * J + c]; \
      w##J##x = t.x; w##J##y = t.y; w##J##z = t.z; w##J##w = t.w; } \
    asm volatile("" : "+v"(w##J##x), "+v"(w##J##y), "+v"(w##J##z), "+v"(w##J##w));
    W_FOREACH(DECL_W)
#undef DECL_W
    const float4 winf = *(const float4*)(Win + (size_t)row * ISIZE + c * 4);

    float hcur = 0.0f;              // this row's h (replicated over the 16 c-lanes)

    for (int k = 1; k <= T_STEPS; ++k) {
        // x load issued before the poll so it's in flight during the spin
        const float4 xv = *(const float4*)(x + (size_t)(k - 1) * ISIZE + c * 4);

        // ---- poll the tagged h_{k-1} words directly (data+tag fused) ----
        const unsigned long long* bp = ((k - 1) & 1) ? buf1 : buf0;
        const unsigned expect = (unsigned)(k - 1);
        unsigned long long w[8];
        unsigned mask = 0xFFu;
        while (mask) {
#pragma unroll
            for (int s = 0; s < 8; ++s) {
                if (mask & (1u << s)) {
                    w[s] = __hip_atomic_load(bp + s * 256 + tid, __ATOMIC_RELAXED,
                                             __HIP_MEMORY_SCOPE_AGENT);
                }
            }
#pragma unroll
            for (int s = 0; s < 8; ++s) {
                if ((mask & (1u << s)) && (unsigned)(w[s] >> 32) == expect) {
                    mask &= ~(1u << s);
                }
            }
        }

        // ---- stage h_{k-1} -> LDS buffer (k&1), stride-1 writes ----
        float* hsb = hs[k & 1];
#pragma unroll
        for (int s = 0; s < 8; ++s) {
            hsb[s * 256 + tid] = __uint_as_float((unsigned)w[s]);
        }
        __syncthreads();   // the ONE barrier per step

        // ---- y[row] = Win[row]·x_{k-1} + Wh[row]·h_{k-1} ----
        float p = winf.x * xv.x + winf.y * xv.y + winf.z * xv.z + winf.w * xv.w;
        const float* hb = hsb + 4 * c;
#define FMA_W(J) { const float4 hv = *(const float4*)(hb + 64 * J); \
                   p += w##J##x * hv.x + w##J##y * hv.y \
                      + w##J##z * hv.z + w##J##w * hv.w; }
        W_FOREACH(FMA_W)
#undef FMA_W

        // butterfly over the 16 c-lanes (c = low 4 lane bits)
        p += __shfl_xor(p, 1);
        p += __shfl_xor(p, 2);
        p += __shfl_xor(p, 4);
        p += __shfl_xor(p, 8);

        // overflow-safe fast tanh: tanh(p) = sign(p) * (1 - 2/(e^{2|p|}+1))
        {
            float ax = fabsf(p);
            float e  = __expf(2.0f * ax);        // v_exp_f32; inf-safe
            float t  = 1.0f - 2.0f / (e + 1.0f);
            t = copysignf(t, p);
            hcur = 0.99f * hcur + 0.01f * t;
        }

        // ---- publish (tag=k, h_k) first, then the output row ----
        if (c == 0) {
            unsigned long long* bc = (k & 1) ? buf1 : buf0;
            unsigned long long wv = ((unsigned long long)(unsigned)k << 32)
                                  | (unsigned long long)__float_as_uint(hcur);
            __hip_atomic_store(bc + row, wv, __ATOMIC_RELAXED,
                               __HIP_MEMORY_SCOPE_AGENT);
            if (k >= WARMUP + 1) {
                out[(size_t)(k - (WARMUP + 1)) * OUTCOLS + row] = hcur;
            }
        }
        // no barrier after publish: next iteration's poll tolerates in-flight
        // stores, and hs reuse is protected by the shared per-step barrier.
    }
}

extern "C" void kernel_launch(void* const* d_in, const int* in_sizes, int n_in,
                              void* d_out, int out_size, void* d_ws, size_t ws_size,
                              hipStream_t stream) {
    const float* x   = (const float*)d_in[0];  // [8192*64]
    const float* Win = (const float*)d_in[1];  // [2048*64]
    const float* Wh  = (const float*)d_in[2];  // [2048*2048]
    float* out = (float*)d_out;                // [8092*2112]

    char* ws = (char*)d_ws;
    unsigned long long* buf0 = (unsigned long long*)ws;            // 16 KB
    unsigned long long* buf1 = (unsigned long long*)(ws + RSIZE * 8);

    // init tagged buffers (ws is poisoned 0xAA before every timed launch)
    init_ws_kernel<<<8, 256, 0, stream>>>(buf0, buf1);

    // x-part of the output, independent of the recurrence
    {
        int n = (T_STEPS - WARMUP) * ISIZE;
        xcopy_kernel<<<(n + 255) / 256, 256, 0, stream>>>(x, out);
    }

    // the sequential scan: 128 persistent workgroups (1 per CU)
    esn_scan_kernel<<<NWG, 256, 0, stream>>>(x, Win, Wh, out, buf0, buf1);
}

// Round 6
// 19384.270 us; speedup vs baseline: 1.4991x; 1.1341x over previous
//
#include <hip/hip_runtime.h>
#include <hip/hip_fp16.h>
#include <math.h>

// ESN recurrence: h_k = 0.99*h_{k-1} + 0.01*tanh(Win x_{k-1} + Wh h_{k-1}), k=1..8192
// out[k-101][0:2048] = h_k (k>=101), out[.][2048:2112] = x_{k-1}
//
// R6: sync-topology restructure.
//  * Broadcast words are 32-bit (tag16<<16 | fp16(h)) -> poll payload halves
//    (8KB/WG/round). Tags k<=8192 fit 16 bits; double-buffering removes reuse
//    ambiguity (stale tag differs by 2). Output stays fp32; only the inter-WG
//    broadcast is fp16.
//  * Each of the 4 waves polls ONLY its 512-row segment, stages it into a
//    wave-PRIVATE padded LDS region (no barrier needed: same-wave lgkmcnt
//    ordering), and computes partials of all 16 WG rows over that segment.
//    The step's single __syncthreads sits AFTER the FMA block, guarding only a
//    64-float cross-wave reduction -> FMA time hides inside broadcast skew.
//  * part[]/hs[] reuse across steps is race-free: wave w can write step-k+1
//    partials only after its segment's k+1 tags exist, which requires some WG
//    to have seen ALL k tags, which requires this WG's wave-0 publish at k,
//    which is program-ordered after wave-0's read of the step-k partials.

#define NWG        128
#define ROWS_PER_WG 16
#define T_STEPS    8192
#define WARMUP     100
#define RSIZE      2048
#define ISIZE      64
#define OUTCOLS    2112
#define SEGPAD     528   // 512 cols + 4-float pad per 128-block (12) + align

__global__ __launch_bounds__(256) void init_ws_kernel(unsigned* buf0, unsigned* buf1) {
    int t = blockIdx.x * blockDim.x + threadIdx.x;
    if (t < RSIZE) {
        buf0[t] = 0u;           // (tag=0, h_0 = fp16 0)
        buf1[t] = 0xFFFF0000u;  // tag 0xFFFF never matches (expects <= 8191)
    }
}

__global__ __launch_bounds__(256) void xcopy_kernel(const float* __restrict__ x,
                                                    float* __restrict__ out) {
    int t = blockIdx.x * blockDim.x + threadIdx.x;
    if (t >= (T_STEPS - WARMUP) * ISIZE) return;
    int rowo = t >> 6;          // output row 0..8091
    int j    = t & 63;
    out[(size_t)rowo * OUTCOLS + RSIZE + j] = x[(size_t)(rowo + WARMUP) * ISIZE + j];
}

static __device__ __forceinline__ float h16_to_f32(unsigned short u) {
    __half_raw hr; hr.x = u;
    return __half2float(__half(hr));
}
static __device__ __forceinline__ unsigned short f32_to_h16(float f) {
    __half_raw hr = __half_raw(__float2half_rn(f));
    return hr.x;
}

#define W_FOREACH(F) \
    F(0)  F(1)  F(2)  F(3)  F(4)  F(5)  F(6)  F(7)  \
    F(8)  F(9)  F(10) F(11) F(12) F(13) F(14) F(15) \
    F(16) F(17) F(18) F(19) F(20) F(21) F(22) F(23) \
    F(24) F(25) F(26) F(27) F(28) F(29) F(30) F(31)

__global__ __launch_bounds__(256, 1) void esn_scan_kernel(
    const float* __restrict__ x,    // [8192][64]
    const float* __restrict__ Win,  // [2048][64]
    const float* __restrict__ Wh,   // [2048][2048]
    float* __restrict__ out,        // [8092][2112]
    unsigned* buf0,                 // [2048] tagged fp16 h words, even steps
    unsigned* buf1)                 // [2048] tagged fp16 h words, odd steps
{
    __shared__ float hs[4 * SEGPAD];  // wave-private padded h segments
    __shared__ float part[64];        // part[r*4 + w]

    const int tid = threadIdx.x;      // 0..255
    const int wg  = blockIdx.x;       // 0..127
    const int w   = tid >> 6;         // wave 0..3  -> h segment [512w, 512w+512)
    const int l   = tid & 63;         // lane
    const int r4  = l >> 2;           // row within WG served by this lane, 0..15
    const int c4  = l & 3;            // 128-col chunk within segment, 0..3
    const int row = wg * ROWS_PER_WG + r4;
    const int seg = w * 512;

    // Pinned weights: Wh[row][seg + c4*128 .. +128) = 32 float4 (128 regs)
    // + Win[row][w*16 + c4*4 .. +4). asm pin keeps them out of the loop
    // (compiler may park them in AGPRs on the unified file — cheap to read).
    const float4* whp4 = (const float4*)(Wh + (size_t)row * RSIZE + seg + c4 * 128);
#define DECL_W(J) \
    float w##J##x, w##J##y, w##J##z, w##J##w; \
    { float4 t = whp4[J]; \
      w##J##x = t.x; w##J##y = t.y; w##J##z = t.z; w##J##w = t.w; } \
    asm volatile("" : "+v"(w##J##x), "+v"(w##J##y), "+v"(w##J##z), "+v"(w##J##w));
    W_FOREACH(DECL_W)
#undef DECL_W
    float wix, wiy, wiz, wiw;
    { float4 t = *(const float4*)(Win + (size_t)row * ISIZE + w * 16 + c4 * 4);
      wix = t.x; wiy = t.y; wiz = t.z; wiw = t.w; }
    asm volatile("" : "+v"(wix), "+v"(wiy), "+v"(wiz), "+v"(wiw));

    float hcur = 0.0f;  // live only in lanes tid<16 (final/publish lanes)

    for (int k = 1; k <= T_STEPS; ++k) {
        // x chunk for this lane's Win partial, in flight during the poll
        const float4 xv = *(const float4*)(x + (size_t)(k - 1) * ISIZE + w * 16 + c4 * 4);

        // ---- poll ONLY this wave's 512-word segment ----
        const unsigned* bp = ((k - 1) & 1) ? buf1 : buf0;
        const unsigned expect = (unsigned)(k - 1) << 16;
        unsigned wv[8];
        unsigned mask = 0xFFu;
        while (mask) {
#pragma unroll
            for (int s = 0; s < 8; ++s) {
                if (mask & (1u << s)) {
                    wv[s] = __hip_atomic_load(bp + w * 512 + s * 64 + l,
                                              __ATOMIC_RELAXED, __HIP_MEMORY_SCOPE_AGENT);
                }
            }
#pragma unroll
            for (int s = 0; s < 8; ++s) {
                if ((mask & (1u << s)) && (wv[s] & 0xFFFF0000u) == expect) {
                    mask &= ~(1u << s);
                }
            }
        }

        // ---- stage segment -> wave-private LDS (padded); NO barrier needed ----
        float* hw = hs + w * SEGPAD;
#pragma unroll
        for (int s = 0; s < 8; ++s) {
            int col  = s * 64 + l;                       // 0..511 within segment
            int addr = col + ((col >> 7) << 2);          // +4 floats per 128-block
            hw[addr] = h16_to_f32((unsigned short)(wv[s] & 0xFFFFu));
        }
        // same-wave ds_write -> ds_read: ordered by lgkmcnt, no __syncthreads

        // ---- partial y[row] over this wave's segment + its x chunk ----
        float p = wix * xv.x + wiy * xv.y + wiz * xv.z + wiw * xv.w;
        const float* hb = hw + c4 * 132;                 // c4*128 + 4*c4 pad
#define FMA_W(J) { const float4 hv = *(const float4*)(hb + 4 * J); \
                   p += w##J##x * hv.x + w##J##y * hv.y \
                      + w##J##z * hv.z + w##J##w * hv.w; }
        W_FOREACH(FMA_W)
#undef FMA_W

        // reduce over the 4 c4 lanes (adjacent lanes)
        p += __shfl_xor(p, 1);
        p += __shfl_xor(p, 2);
        if (c4 == 0) part[r4 * 4 + w] = p;

        __syncthreads();   // the ONE barrier: guards the 64-float reduction

        // ---- final lanes: combine 4 wave-partials, activate, publish ----
        if (tid < 16) {
            const float4 ps = *(const float4*)(part + tid * 4);
            float y = ps.x + ps.y + ps.z + ps.w;
            // overflow-safe fast tanh
            float ax = fabsf(y);
            float e  = __expf(2.0f * ax);
            float t  = 1.0f - 2.0f / (e + 1.0f);
            t = copysignf(t, y);
            hcur = 0.99f * hcur + 0.01f * t;

            // publish first (broadcast critical path), then the output row
            unsigned* bc = (k & 1) ? buf1 : buf0;
            unsigned word = ((unsigned)k << 16) | (unsigned)f32_to_h16(hcur);
            __hip_atomic_store(bc + wg * ROWS_PER_WG + tid, word,
                               __ATOMIC_RELAXED, __HIP_MEMORY_SCOPE_AGENT);
            if (k >= WARMUP + 1) {
                out[(size_t)(k - (WARMUP + 1)) * OUTCOLS + wg * ROWS_PER_WG + tid] = hcur;
            }
        }
        // no second barrier: hs is wave-private; part reuse is protected by the
        // global publish->poll dependency chain (see header comment).
    }
}

extern "C" void kernel_launch(void* const* d_in, const int* in_sizes, int n_in,
                              void* d_out, int out_size, void* d_ws, size_t ws_size,
                              hipStream_t stream) {
    const float* x   = (const float*)d_in[0];  // [8192*64]
    const float* Win = (const float*)d_in[1];  // [2048*64]
    const float* Wh  = (const float*)d_in[2];  // [2048*2048]
    float* out = (float*)d_out;                // [8092*2112]

    char* ws = (char*)d_ws;
    unsigned* buf0 = (unsigned*)ws;                    // 8 KB
    unsigned* buf1 = (unsigned*)(ws + RSIZE * 4);      // 8 KB

    // init tagged buffers (ws is poisoned 0xAA before every timed launch)
    init_ws_kernel<<<8, 256, 0, stream>>>(buf0, buf1);

    // x-part of the output, independent of the recurrence
    {
        int n = (T_STEPS - WARMUP) * ISIZE;
        xcopy_kernel<<<(n + 255) / 256, 256, 0, stream>>>(x, out);
    }

    // the sequential scan: 128 persistent workgroups (1 per CU)
    esn_scan_kernel<<<NWG, 256, 0, stream>>>(x, Win, Wh, out, buf0, buf1);
}

// Round 7
// 18364.642 us; speedup vs baseline: 1.5823x; 1.0555x over previous
//
#include <hip/hip_runtime.h>
#include <hip/hip_fp16.h>
#include <math.h>

// ESN recurrence: h_k = 0.99*h_{k-1} + 0.01*tanh(Win x_{k-1} + Wh h_{k-1}), k=1..8192
// out[k-101][0:2048] = h_k (k>=101), out[.][2048:2112] = x_{k-1}
//
// R7: attack L3-slice congestion on the broadcast buffer.
//  * 8 replicas of the tagged fp16 h buffer, 64 KB apart (distinct L3/HBM
//    channel stripes). Producers store their 16 words to ALL replicas
//    (fire-and-forget); consumers poll only replica wg&7 -> per-replica load
//    pressure drops 8x (and request count per lane 2x via b64 polls).
//  * Poll with 8-byte agent-scope atomic loads, lane-pair mapping
//    (pair s covers words s*128 + 2l): 4 perfectly-coalesced requests per
//    lane per round. Staging becomes ds_write_b64, uniform 4-way bank
//    aliasing (~free per m136).
//  * Race-free: every publish word's VALUE data-depends on all step-(k-1)
//    words its WG polled, so a slot is overwritten (tag k+2) only after every
//    consumer of that replica has read tag k. Same chain as R2-R6, per replica.

#define NWG        128
#define ROWS_PER_WG 16
#define T_STEPS    8192
#define WARMUP     100
#define RSIZE      2048
#define ISIZE      64
#define OUTCOLS    2112
#define SEGPAD     528        // 4 blocks of 132 floats (128 + 4 pad)
#define MAXREP     8
#define REP_STRIDE_W 16384    // 64 KB / 4B between replica bases

__global__ __launch_bounds__(256) void init_ws_kernel(unsigned* rep0, int nrep) {
    int t = blockIdx.x * blockDim.x + threadIdx.x;
    if (t < nrep * RSIZE) {
        int rep = t >> 11;          // RSIZE = 2048
        int idx = t & (RSIZE - 1);
        unsigned* b = rep0 + rep * REP_STRIDE_W;
        b[idx]         = 0u;           // buf0: (tag=0, h_0 = fp16 0)
        b[RSIZE + idx] = 0xFFFF0000u;  // buf1: tag 0xFFFF never matches
    }
}

__global__ __launch_bounds__(256) void xcopy_kernel(const float* __restrict__ x,
                                                    float* __restrict__ out) {
    int t = blockIdx.x * blockDim.x + threadIdx.x;
    if (t >= (T_STEPS - WARMUP) * ISIZE) return;
    int rowo = t >> 6;          // output row 0..8091
    int j    = t & 63;
    out[(size_t)rowo * OUTCOLS + RSIZE + j] = x[(size_t)(rowo + WARMUP) * ISIZE + j];
}

static __device__ __forceinline__ float h16_to_f32(unsigned short u) {
    __half_raw hr; hr.x = u;
    return __half2float(__half(hr));
}
static __device__ __forceinline__ unsigned short f32_to_h16(float f) {
    __half_raw hr = __half_raw(__float2half_rn(f));
    return hr.x;
}

#define W_FOREACH(F) \
    F(0)  F(1)  F(2)  F(3)  F(4)  F(5)  F(6)  F(7)  \
    F(8)  F(9)  F(10) F(11) F(12) F(13) F(14) F(15) \
    F(16) F(17) F(18) F(19) F(20) F(21) F(22) F(23) \
    F(24) F(25) F(26) F(27) F(28) F(29) F(30) F(31)

__global__ __launch_bounds__(256, 1) void esn_scan_kernel(
    const float* __restrict__ x,    // [8192][64]
    const float* __restrict__ Win,  // [2048][64]
    const float* __restrict__ Wh,   // [2048][2048]
    float* __restrict__ out,        // [8092][2112]
    unsigned* rep0,                 // replica 0 base; replicas at +r*REP_STRIDE_W
    int nrep, int repmask)          // nrep = pow2 in [1,8], repmask = nrep-1
{
    __shared__ float hs[4 * SEGPAD];  // wave-private padded h segments
    __shared__ float part[64];        // part[r*4 + w]

    const int tid = threadIdx.x;      // 0..255
    const int wg  = blockIdx.x;       // 0..127
    const int w   = tid >> 6;         // wave 0..3 -> h segment [512w, 512w+512)
    const int l   = tid & 63;         // lane
    const int r4  = l >> 2;           // row within WG served by this lane, 0..15
    const int c4  = l & 3;            // 128-col chunk within segment, 0..3
    const int row = wg * ROWS_PER_WG + r4;
    const int seg = w * 512;

    // My poll replica (fixed per WG)
    const unsigned* myrep = rep0 + (wg & repmask) * REP_STRIDE_W;

    // Pinned weights: Wh[row][seg + c4*128 .. +128) = 32 float4 (128 regs)
    const float4* whp4 = (const float4*)(Wh + (size_t)row * RSIZE + seg + c4 * 128);
#define DECL_W(J) \
    float w##J##x, w##J##y, w##J##z, w##J##w; \
    { float4 t = whp4[J]; \
      w##J##x = t.x; w##J##y = t.y; w##J##z = t.z; w##J##w = t.w; } \
    asm volatile("" : "+v"(w##J##x), "+v"(w##J##y), "+v"(w##J##z), "+v"(w##J##w));
    W_FOREACH(DECL_W)
#undef DECL_W
    float wix, wiy, wiz, wiw;
    { float4 t = *(const float4*)(Win + (size_t)row * ISIZE + w * 16 + c4 * 4);
      wix = t.x; wiy = t.y; wiz = t.z; wiw = t.w; }
    asm volatile("" : "+v"(wix), "+v"(wiy), "+v"(wiz), "+v"(wiw));

    float hcur = 0.0f;  // live only in lanes tid<16 (publish lanes)

    for (int k = 1; k <= T_STEPS; ++k) {
        // x chunk in flight during the poll
        const float4 xv = *(const float4*)(x + (size_t)(k - 1) * ISIZE + w * 16 + c4 * 4);

        // ---- poll my replica's segment: 4 coalesced b64 loads ----
        // pair s holds segment words {s*128 + 2l, s*128 + 2l + 1}
        const unsigned* bp = myrep + (((k - 1) & 1) ? RSIZE : 0) + seg;
        const unsigned long long exp64 =
            ((unsigned long long)(unsigned)(k - 1) << 16) * 0x100000001ull; // both halves
        unsigned long long q[4];
        unsigned m = 0xFu;
        while (m) {
#pragma unroll
            for (int s = 0; s < 4; ++s) {
                if (m & (1u << s)) {
                    q[s] = __hip_atomic_load(
                        (const unsigned long long*)(bp + s * 128 + 2 * l),
                        __ATOMIC_RELAXED, __HIP_MEMORY_SCOPE_AGENT);
                }
            }
#pragma unroll
            for (int s = 0; s < 4; ++s) {
                if ((m & (1u << s)) &&
                    (q[s] & 0xFFFF0000FFFF0000ull) == exp64) {
                    m &= ~(1u << s);
                }
            }
        }

        // ---- stage segment -> wave-private LDS (padded); no barrier needed ----
        float* hw = hs + w * SEGPAD;
#pragma unroll
        for (int s = 0; s < 4; ++s) {
            // block index within segment == s; padded base = 132*s
            float2* d = (float2*)(hw + 132 * s + 2 * l);
            float2 v;
            v.x = h16_to_f32((unsigned short)(q[s] & 0xFFFFu));
            v.y = h16_to_f32((unsigned short)((q[s] >> 32) & 0xFFFFu));
            *d = v;
        }
        // same-wave ds_write -> ds_read ordered by lgkmcnt

        // ---- partial y[row] over this wave's segment + its x chunk ----
        float p = wix * xv.x + wiy * xv.y + wiz * xv.z + wiw * xv.w;
        const float* hb = hw + c4 * 132;
#define FMA_W(J) { const float4 hv = *(const float4*)(hb + 4 * J); \
                   p += w##J##x * hv.x + w##J##y * hv.y \
                      + w##J##z * hv.z + w##J##w * hv.w; }
        W_FOREACH(FMA_W)
#undef FMA_W

        // reduce over the 4 c4 lanes
        p += __shfl_xor(p, 1);
        p += __shfl_xor(p, 2);
        if (c4 == 0) part[r4 * 4 + w] = p;

        __syncthreads();   // the ONE barrier: guards the 64-float reduction

        // ---- publish lanes: combine, activate, publish to ALL replicas ----
        if (tid < 16) {
            const float4 ps = *(const float4*)(part + tid * 4);
            float y = ps.x + ps.y + ps.z + ps.w;
            float ax = fabsf(y);
            float e  = __expf(2.0f * ax);
            float t  = 1.0f - 2.0f / (e + 1.0f);
            t = copysignf(t, y);
            hcur = 0.99f * hcur + 0.01f * t;

            unsigned word = ((unsigned)k << 16) | (unsigned)f32_to_h16(hcur);
            const int slot = ((k & 1) ? RSIZE : 0) + wg * ROWS_PER_WG + tid;
#pragma unroll
            for (int rr = 0; rr < MAXREP; ++rr) {
                if (rr < nrep) {
                    __hip_atomic_store(rep0 + rr * REP_STRIDE_W + slot, word,
                                       __ATOMIC_RELAXED, __HIP_MEMORY_SCOPE_AGENT);
                }
            }
            if (k >= WARMUP + 1) {
                out[(size_t)(k - (WARMUP + 1)) * OUTCOLS + wg * ROWS_PER_WG + tid] = hcur;
            }
        }
        // no second barrier: hs wave-private; part[] reuse protected by the
        // global publish->poll dependency chain (see header comment).
    }
}

extern "C" void kernel_launch(void* const* d_in, const int* in_sizes, int n_in,
                              void* d_out, int out_size, void* d_ws, size_t ws_size,
                              hipStream_t stream) {
    const float* x   = (const float*)d_in[0];  // [8192*64]
    const float* Win = (const float*)d_in[1];  // [2048*64]
    const float* Wh  = (const float*)d_in[2];  // [2048*2048]
    float* out = (float*)d_out;                // [8092*2112]

    unsigned* rep0 = (unsigned*)d_ws;

    // nrep = largest power of two <= min(8, ws_size / 64KB)
    int nrep = MAXREP;
    while (nrep > 1 && (size_t)nrep * (REP_STRIDE_W * 4) > ws_size) nrep >>= 1;
    int repmask = nrep - 1;

    // init all replicas (ws is poisoned 0xAA before every timed launch)
    {
        int n = nrep * RSIZE;
        init_ws_kernel<<<(n + 255) / 256, 256, 0, stream>>>(rep0, nrep);
    }

    // x-part of the output, independent of the recurrence
    {
        int n = (T_STEPS - WARMUP) * ISIZE;
        xcopy_kernel<<<(n + 255) / 256, 256, 0, stream>>>(x, out);
    }

    // the sequential scan: 128 persistent workgroups (1 per CU)
    esn_scan_kernel<<<NWG, 256, 0, stream>>>(x, Win, Wh, out, rep0, nrep, repmask);
}